// Round 1
// baseline (46742.606 us; speedup 1.0000x reference)
//
#include <hip/hip_runtime.h>
#include <math.h>

// Problem dims
#define NWG 256
#define NTHR 512
static constexpr int S = 512, B = 64, I = 128, H = 512;

// ws layout (float units)
//  buf0 : S*B*H          = 16777216   (x_proj, overwritten in-place by out_pre)
//  pctx : B*4*H          = 131072
//  pml  : B*4*2          = 512
//  h2   : 2*B*H          = 65536      (pre-RNN h double buffer)
//  h3   : 2*B*H          = 65536      (attention h double buffer)
//  bar  : 2 uints
// total ≈ 68,159,496 bytes required in ws
static constexpr size_t OFF_BUF0 = 0;
static constexpr size_t OFF_PCTX = 16777216;
static constexpr size_t OFF_PML  = OFF_PCTX + (size_t)B * 4 * H;
static constexpr size_t OFF_H2   = OFF_PML + (size_t)B * 4 * 2;
static constexpr size_t OFF_H3   = OFF_H2 + (size_t)2 * B * H;
static constexpr size_t OFF_BAR  = OFF_H3 + (size_t)2 * B * H;

// Grid-wide barrier: gen-counter, device(agent)-scope acq/rel.
__device__ __forceinline__ void gbar(unsigned* __restrict__ bar) {
  __syncthreads();
  if (threadIdx.x == 0) {
    unsigned g = __hip_atomic_load(bar + 1, __ATOMIC_RELAXED, __HIP_MEMORY_SCOPE_AGENT);
    unsigned a = __hip_atomic_fetch_add(bar, 1u, __ATOMIC_ACQ_REL, __HIP_MEMORY_SCOPE_AGENT);
    if (a == (unsigned)(NWG - 1)) {
      __hip_atomic_store(bar, 0u, __ATOMIC_RELAXED, __HIP_MEMORY_SCOPE_AGENT);
      __hip_atomic_store(bar + 1, g + 1u, __ATOMIC_RELEASE, __HIP_MEMORY_SCOPE_AGENT);
    } else {
      while (__hip_atomic_load(bar + 1, __ATOMIC_ACQUIRE, __HIP_MEMORY_SCOPE_AGENT) == g) {
        __builtin_amdgcn_s_sleep(1);
      }
    }
  }
  __syncthreads();
}

__global__ __launch_bounds__(NTHR, 2) void attn_fused(
    const float* __restrict__ inputs,
    const float* __restrict__ Wih_pre, const float* __restrict__ Whh_pre,
    const float* __restrict__ bih_pre, const float* __restrict__ bhh_pre,
    const float* __restrict__ Wih_post, const float* __restrict__ Whh_post,
    const float* __restrict__ bih_post, const float* __restrict__ bhh_post,
    const float* __restrict__ Wfc, const float* __restrict__ bfc,
    float* __restrict__ out, float* __restrict__ ws)
{
  float* buf0 = ws + OFF_BUF0;
  float* pctx = ws + OFF_PCTX;
  float* pml  = ws + OFF_PML;
  float* h2   = ws + OFF_H2;
  float* h3   = ws + OFF_H3;
  unsigned* bar = (unsigned*)(ws + OFF_BAR);

  const int wg   = blockIdx.x;
  const int tid  = threadIdx.x;
  const int lane = tid & 63;
  const int wv   = tid >> 6;   // wave id 0..7

  __shared__ float smem[8256];  // 33 KB: P1 tile / 3a merge / 3c staging

  // ================= P1: x_proj = inputs @ W_ih_pre^T + (b_ih+b_hh) ==========
  {
    const int h = tid;  // 512 threads = 512 h columns
    float4 Wr[32];      // full W row (128 fp32) stationary in regs
    const float4* wrow = (const float4*)(Wih_pre + (size_t)h * I);
    #pragma unroll
    for (int c = 0; c < 32; ++c) Wr[c] = wrow[c];
    const float bias = bih_pre[h] + bhh_pre[h];
    const int r0 = wg * 128;  // 128 flattened (s*B+b) rows per WG
    for (int t2 = 0; t2 < 2; ++t2) {
      __syncthreads();
      const float4* src = (const float4*)(inputs + (size_t)(r0 + t2 * 64) * I);
      for (int idx = tid; idx < 64 * I / 4; idx += NTHR)
        ((float4*)smem)[idx] = src[idx];
      __syncthreads();
      for (int r = 0; r < 64; ++r) {
        const float4* arow = (const float4*)(smem + r * I);
        float acc0 = 0.f, acc1 = 0.f;
        #pragma unroll
        for (int c = 0; c < 32; c += 2) {
          float4 a0 = arow[c], a1 = arow[c + 1];
          acc0 += a0.x * Wr[c].x + a0.y * Wr[c].y + a0.z * Wr[c].z + a0.w * Wr[c].w;
          acc1 += a1.x * Wr[c+1].x + a1.y * Wr[c+1].y + a1.z * Wr[c+1].z + a1.w * Wr[c+1].w;
        }
        buf0[(size_t)(r0 + t2 * 64 + r) * H + h] = acc0 + acc1 + bias;
      }
    }
  }
  gbar(bar);

  // ================= P2: pre-RNN, 512 sequential steps ======================
  // WG = (bg 0..7) x (jg 0..31); wave handles j-pair {j0, j0+1} for 8 batches.
  {
    const int bg = wg >> 5;
    const int jg = wg & 31;
    const int j0 = jg * 16 + wv * 2;
    float w0[8], w1[8];  // W_hh rows stationary
    #pragma unroll
    for (int ki = 0; ki < 8; ++ki) {
      w0[ki] = Whh_pre[(size_t)j0 * H + lane + 64 * ki];
      w1[ki] = Whh_pre[(size_t)(j0 + 1) * H + lane + 64 * ki];
    }
    for (int t = 0; t < S; ++t) {
      const float* hin = h2 + (size_t)(t & 1) * (B * H);
      float* hout      = h2 + (size_t)((t + 1) & 1) * (B * H);
      for (int bi = 0; bi < 8; ++bi) {
        const int b = bg * 8 + bi;
        const size_t xoff = ((size_t)t * B + b) * H + j0;
        float xp0 = buf0[xoff];        // includes both biases
        float xp1 = buf0[xoff + 1];
        float hk[8];
        #pragma unroll
        for (int ki = 0; ki < 8; ++ki) hk[ki] = hin[(size_t)b * H + lane + 64 * ki];
        float d0 = 0.f, d1 = 0.f;
        #pragma unroll
        for (int ki = 0; ki < 8; ++ki) { d0 += hk[ki] * w0[ki]; d1 += hk[ki] * w1[ki]; }
        #pragma unroll
        for (int off = 32; off > 0; off >>= 1) {
          d0 += __shfl_xor(d0, off);
          d1 += __shfl_xor(d1, off);
        }
        float h0n = tanhf(xp0 + d0);
        float h1n = tanhf(xp1 + d1);
        if (lane == 0) {
          hout[(size_t)b * H + j0]     = h0n;
          hout[(size_t)b * H + j0 + 1] = h1n;
          buf0[xoff]     = h0n;   // out_pre overwrites x_proj in place
          buf0[xoff + 1] = h1n;
        }
      }
      gbar(bar);
    }
  }

  // ================= P3: attention loop, 512 sequential steps ================
  const int b3    = wg >> 2;   // 3a: batch
  const int strip = wg & 3;    // 3a: s-strip (128 s each)
  const int bg    = wg >> 5;   // 3c: batch group (8 batches)
  const int jg    = wg & 31;   // 3c: j group (16 j)
  const int j0    = jg * 16 + wv * 2;

  // [W_ih_post | W_hh_post] rows stationary in regs for 3c
  float wc0[16], wc1[16];
  #pragma unroll
  for (int ki = 0; ki < 16; ++ki) {
    int k = lane + 64 * ki;
    wc0[ki] = (k < H) ? Wih_post[(size_t)j0 * H + k] : Whh_post[(size_t)j0 * H + (k - H)];
    wc1[ki] = (k < H) ? Wih_post[(size_t)(j0 + 1) * H + k] : Whh_post[(size_t)(j0 + 1) * H + (k - H)];
  }
  const float bp0 = bih_post[j0] + bhh_post[j0];
  const float bp1 = bih_post[j0 + 1] + bhh_post[j0 + 1];

  for (int u = 0; u < H; ++u) {
    const float* hin = h3 + (size_t)(u & 1) * (B * H);
    float* hout      = h3 + (size_t)((u + 1) & 1) * (B * H);

    // ---- 3a: fused scores + online softmax + ctx partial (one pass over M_b strip)
    {
      const float* hb = hin + (size_t)b3 * H;
      float4 hA = *(const float4*)(hb + lane * 4);
      float4 hB = *(const float4*)(hb + 256 + lane * 4);
      float m = -1e30f, l = 0.f;
      float4 cA{0.f,0.f,0.f,0.f}, cB{0.f,0.f,0.f,0.f};
      const int sbase = strip * 128 + wv;  // wave covers 16 s, stride 8
      const float* row0 = buf0 + ((size_t)sbase * B + b3) * H;
      float4 pA = *(const float4*)(row0 + lane * 4);
      float4 pB = *(const float4*)(row0 + 256 + lane * 4);
      for (int i = 0; i < 16; ++i) {
        float4 rA = pA, rB = pB;
        if (i < 15) {
          const float* nrow = buf0 + ((size_t)(sbase + 8 * (i + 1)) * B + b3) * H;
          pA = *(const float4*)(nrow + lane * 4);
          pB = *(const float4*)(nrow + 256 + lane * 4);
        }
        float da = rA.x * hA.x + rA.y * hA.y + rA.z * hA.z + rA.w * hA.w;
        float db = rB.x * hB.x + rB.y * hB.y + rB.z * hB.z + rB.w * hB.w;
        float d = da + db;
        #pragma unroll
        for (int off = 32; off > 0; off >>= 1) d += __shfl_xor(d, off);
        float mn = fmaxf(m, d);
        float a = __expf(m - mn);
        float e = __expf(d - mn);
        cA.x = cA.x * a + e * rA.x;  cA.y = cA.y * a + e * rA.y;
        cA.z = cA.z * a + e * rA.z;  cA.w = cA.w * a + e * rA.w;
        cB.x = cB.x * a + e * rB.x;  cB.y = cB.y * a + e * rB.y;
        cB.z = cB.z * a + e * rB.z;  cB.w = cB.w * a + e * rB.w;
        l = l * a + e;
        m = mn;
      }
      // merge 8 waves in LDS
      float* ctx_lds = smem;          // [8][512]
      float* ml_lds  = smem + 4096;   // [8][2]
      *(float4*)(ctx_lds + wv * 512 + lane * 4) = cA;
      *(float4*)(ctx_lds + wv * 512 + 256 + lane * 4) = cB;
      if (lane == 0) { ml_lds[wv * 2] = m; ml_lds[wv * 2 + 1] = l; }
      __syncthreads();
      float mstar = -1e30f;
      #pragma unroll
      for (int w = 0; w < 8; ++w) mstar = fmaxf(mstar, ml_lds[w * 2]);
      float lsum = 0.f, csum = 0.f;
      #pragma unroll
      for (int w = 0; w < 8; ++w) {
        float sc = __expf(ml_lds[w * 2] - mstar);
        lsum += sc * ml_lds[w * 2 + 1];
        csum += sc * ctx_lds[w * 512 + tid];
      }
      pctx[((size_t)b3 * 4 + strip) * H + tid] = csum;
      if (tid == 0) {
        pml[((size_t)b3 * 4 + strip) * 2]     = mstar;
        pml[((size_t)b3 * 4 + strip) * 2 + 1] = lsum;
      }
    }
    gbar(bar);

    // ---- 3c: merge strip partials -> ctx; h-update GEMV with stationary W
    {
      float* ctx2 = smem;         // [8][512]
      float* hst  = smem + 4096;  // [8][512]
      for (int bi = 0; bi < 8; ++bi) {
        const int b = bg * 8 + bi;
        const float* ml = pml + (size_t)b * 8;
        float m0 = ml[0], l0 = ml[1], m1 = ml[2], l1 = ml[3];
        float m2 = ml[4], l2 = ml[5], m3 = ml[6], l3 = ml[7];
        float mb = fmaxf(fmaxf(m0, m1), fmaxf(m2, m3));
        float s0 = __expf(m0 - mb), s1 = __expf(m1 - mb);
        float s2 = __expf(m2 - mb), s3 = __expf(m3 - mb);
        float inv = 1.0f / (s0 * l0 + s1 * l1 + s2 * l2 + s3 * l3);
        const float* pc = pctx + (size_t)b * 4 * H;
        float c = (s0 * pc[0 * H + tid] + s1 * pc[1 * H + tid] +
                   s2 * pc[2 * H + tid] + s3 * pc[3 * H + tid]) * inv;
        ctx2[bi * H + tid] = c;
        hst[bi * H + tid]  = hin[(size_t)b * H + tid];
      }
      __syncthreads();
      for (int bi = 0; bi < 8; ++bi) {
        float d0 = 0.f, d1 = 0.f;
        #pragma unroll
        for (int ki = 0; ki < 16; ++ki) {
          int kk = lane + 64 * ki;
          float v = (ki < 8) ? ctx2[bi * H + kk] : hst[bi * H + (kk - H)];
          d0 += v * wc0[ki];
          d1 += v * wc1[ki];
        }
        #pragma unroll
        for (int off = 32; off > 0; off >>= 1) {
          d0 += __shfl_xor(d0, off);
          d1 += __shfl_xor(d1, off);
        }
        float h0n = tanhf(d0 + bp0);
        float h1n = tanhf(d1 + bp1);
        if (lane == 0) {
          const int b = bg * 8 + bi;
          hout[(size_t)b * H + j0]     = h0n;
          hout[(size_t)b * H + j0 + 1] = h1n;
        }
      }
    }
    gbar(bar);
  }

  // ================= final: out = h_post @ W_fc^T + b_fc =====================
  if (wg == 0) {
    const float* hf = h3;  // 512 steps -> final parity slot 0
    for (int i = 0; i < 8; ++i) {
      const int b = wv * 8 + i;
      float d = 0.f;
      #pragma unroll
      for (int ki = 0; ki < 8; ++ki) {
        int k = lane + 64 * ki;
        d += hf[(size_t)b * H + k] * Wfc[k];
      }
      #pragma unroll
      for (int off = 32; off > 0; off >>= 1) d += __shfl_xor(d, off);
      if (lane == 0) out[b] = d + bfc[0];
    }
  }
}

extern "C" void kernel_launch(void* const* d_in, const int* in_sizes, int n_in,
                              void* d_out, int out_size, void* d_ws, size_t ws_size,
                              hipStream_t stream) {
  (void)in_sizes; (void)n_in; (void)out_size; (void)ws_size;
  const float* inputs   = (const float*)d_in[0];
  const float* Wih_pre  = (const float*)d_in[1];
  const float* Whh_pre  = (const float*)d_in[2];
  const float* bih_pre  = (const float*)d_in[3];
  const float* bhh_pre  = (const float*)d_in[4];
  const float* Wih_post = (const float*)d_in[5];
  const float* Whh_post = (const float*)d_in[6];
  const float* bih_post = (const float*)d_in[7];
  const float* bhh_post = (const float*)d_in[8];
  const float* Wfc      = (const float*)d_in[9];
  const float* bfc      = (const float*)d_in[10];
  float* out = (float*)d_out;
  float* ws  = (float*)d_ws;

  // Zero h double-buffers + barrier state every launch (deterministic under
  // graph replay; ws is poisoned 0xAA once and never re-poisoned).
  size_t zoff = OFF_H2 * sizeof(float);
  size_t zlen = (OFF_BAR - OFF_H2) * sizeof(float) + 8;
  hipMemsetAsync((char*)d_ws + zoff, 0, zlen, stream);

  attn_fused<<<dim3(NWG), dim3(NTHR), 0, stream>>>(
      inputs, Wih_pre, Whh_pre, bih_pre, bhh_pre,
      Wih_post, Whh_post, bih_post, bhh_post, Wfc, bfc, out, ws);
}